// Round 4
// baseline (441.839 us; speedup 1.0000x reference)
//
#include <hip/hip_runtime.h>
#include <hip/hip_bf16.h>
#include <stdint.h>

// Problem: out = x_norm + dropout(relu(LN(x) @ W1) @ W2), B=4,S=2048,D=2048
#define M_DIM 8192   // B*S
#define N_DIM 2048
#define K_DIM 2048

typedef __bf16 bf16x8_t __attribute__((ext_vector_type(8)));
typedef float f32x4_t __attribute__((ext_vector_type(4)));

// ---------------- threefry2x32, JAX partitionable path, key=(0,1) -------------
// bits(j) = o0^o1 of threefry2x32(key=(0,1), ctr=(0, j)); keep iff bits < 0xC0000000.
// Verified round 1: absmax 0.0625 -> mask exact.
__device__ __forceinline__ unsigned tf_rotl(unsigned x, int r) {
  return (x << r) | (x >> (32 - r));
}
__device__ __forceinline__ unsigned threefry_mask_bits(unsigned ctr) {
  unsigned x0 = 0u, x1 = ctr;
  const unsigned ks0 = 0u, ks1 = 1u, ks2 = 0x1BD11BDBu;
  x0 += ks0; x1 += ks1;
#define TFR(r) { x0 += x1; x1 = tf_rotl(x1, (r)); x1 ^= x0; }
  TFR(13) TFR(15) TFR(26) TFR(6)
  x0 += ks1; x1 += ks2 + 1u;
  TFR(17) TFR(29) TFR(16) TFR(24)
  x0 += ks2; x1 += ks0 + 2u;
  TFR(13) TFR(15) TFR(26) TFR(6)
  x0 += ks0; x1 += ks1 + 3u;
  TFR(17) TFR(29) TFR(16) TFR(24)
  x0 += ks1; x1 += ks2 + 4u;
  TFR(13) TFR(15) TFR(26) TFR(6)
  x0 += ks2; x1 += ks0 + 5u;
#undef TFR
  return x0 ^ x1;
}

// ---------------- async global->LDS, 16B per lane -----------------------------
__device__ __forceinline__ void gload_lds16(const __hip_bfloat16* g, unsigned short* l) {
  __builtin_amdgcn_global_load_lds(
      (const __attribute__((address_space(1))) unsigned int*)g,
      (__attribute__((address_space(3))) unsigned int*)l,
      16, 0, 0);
}

// ---------------- W [K][N] fp32 -> Wt [N][K] bf16 -----------------------------
__global__ __launch_bounds__(256) void wt_kernel(
    const float* __restrict__ W1, const float* __restrict__ W2,
    __hip_bfloat16* __restrict__ W1t, __hip_bfloat16* __restrict__ W2t) {
  __shared__ float tile[32][33];
  const float* src = blockIdx.z ? W2 : W1;
  __hip_bfloat16* dst = blockIdx.z ? W2t : W1t;
  int x = blockIdx.x * 32 + threadIdx.x;
  int y = blockIdx.y * 32 + threadIdx.y;
#pragma unroll
  for (int i = 0; i < 32; i += 8)
    tile[threadIdx.y + i][threadIdx.x] = src[(size_t)(y + i) * N_DIM + x];
  __syncthreads();
  int xo = blockIdx.y * 32 + threadIdx.x;
  int yo = blockIdx.x * 32 + threadIdx.y;
#pragma unroll
  for (int i = 0; i < 32; i += 8)
    dst[(size_t)(yo + i) * K_DIM + xo] = __float2bfloat16(tile[threadIdx.x][threadIdx.y + i]);
}

// ---------------- LayerNorm (no affine) -> bf16 -------------------------------
__global__ __launch_bounds__(256) void ln_kernel(const float* __restrict__ X,
                                                 __hip_bfloat16* __restrict__ Xn) {
  const int row = blockIdx.x;
  const float4* xv = (const float4*)(X + (size_t)row * K_DIM);
  float4 v0 = xv[threadIdx.x];
  float4 v1 = xv[threadIdx.x + 256];
  float s  = v0.x + v0.y + v0.z + v0.w + v1.x + v1.y + v1.z + v1.w;
  float ss = v0.x*v0.x + v0.y*v0.y + v0.z*v0.z + v0.w*v0.w
           + v1.x*v1.x + v1.y*v1.y + v1.z*v1.z + v1.w*v1.w;
#pragma unroll
  for (int off = 32; off > 0; off >>= 1) {
    s  += __shfl_xor(s, off);
    ss += __shfl_xor(ss, off);
  }
  __shared__ float rs[4], rss[4];
  const int wave = threadIdx.x >> 6;
  if ((threadIdx.x & 63) == 0) { rs[wave] = s; rss[wave] = ss; }
  __syncthreads();
  float S  = rs[0] + rs[1] + rs[2] + rs[3];
  float SS = rss[0] + rss[1] + rss[2] + rss[3];
  float mean = S * (1.0f / 2048.0f);
  float var  = SS * (1.0f / 2048.0f) - mean * mean;
  float rstd = 1.0f / sqrtf(var + 1e-6f);
  float vv[8] = {v0.x, v0.y, v0.z, v0.w, v1.x, v1.y, v1.z, v1.w};
  unsigned short o[8];
#pragma unroll
  for (int i = 0; i < 8; i++) {
    __hip_bfloat16 b = __float2bfloat16((vv[i] - mean) * rstd);
    o[i] = *(unsigned short*)&b;
  }
  ushort4* dst = (ushort4*)(Xn + (size_t)row * K_DIM);
  dst[threadIdx.x]       = make_ushort4(o[0], o[1], o[2], o[3]);
  dst[threadIdx.x + 256] = make_ushort4(o[4], o[5], o[6], o[7]);
}

// ---------------- 128x128 MFMA GEMM, A-direct-from-global, B via LDS ----------
// A[M][K], Bt[N][K] bf16. EPI=0: H=relu(A@B)->bf16. EPI=1: out=Xn+dropout/0.75.
// Round-3 analysis: LDS pipe was the binding resource (96 KB/iter/block vs
// 85 B/cyc). A-fragments are 16B-contiguous in global (K-major), so load them
// straight to VGPRs (register-double-buffered, 1-iter prefetch distance);
// only B is staged through LDS (XOR-swizzled, conflict-free).
// LDS/iter/block: 32 KB read + 16 KB write (was 96 KB).
template <int EPI>
__global__ __launch_bounds__(256, 2) void gemm128(
    const __hip_bfloat16* __restrict__ A,
    const __hip_bfloat16* __restrict__ Bt,
    const __hip_bfloat16* __restrict__ Xn,   // EPI=1 residual
    __hip_bfloat16* __restrict__ Hout,       // EPI=0 output
    float* __restrict__ Fout) {              // EPI=1 output
  __shared__ unsigned short Bs[2][128 * 64];  // 32 KB total
  const int tid  = threadIdx.x;
  const int lane = tid & 63;
  const int wave = tid >> 6;
  const int wm = wave >> 1, wn = wave & 1;
  // grid: x walks M (fastest) -> consecutive blocks share the B panel in L2;
  // co-resident blocks (id, id+512) share the A panel (same x).
  const int mBase = blockIdx.x * 128;
  const int nBase = blockIdx.y * 128;

  f32x4_t acc[4][4];
#pragma unroll
  for (int i = 0; i < 4; i++)
#pragma unroll
    for (int j = 0; j < 4; j++) acc[i][j] = (f32x4_t){0.f, 0.f, 0.f, 0.f};

  // ---- B staging: 16 KB/stage = 16 chunks of 1 KB (8 n-rows x 128 B).
  // wave w loads chunks {w, w+4, w+8, w+12}. lane l covers row 8*ca + (l>>3),
  // source k-chunk (l&7)^((l>>3)&7) (XOR swizzle; verified conflict-free r3).
  const int rowIn = lane >> 3;
  const int csrc  = ((lane & 7) ^ (rowIn & 7)) << 3;
  const __hip_bfloat16* bSrc[4];
  int sDst[4];
#pragma unroll
  for (int j = 0; j < 4; j++) {
    const int ca = wave + 4 * j;
    bSrc[j] = Bt + (size_t)(nBase + 8 * ca + rowIn) * K_DIM + csrc;
    sDst[j] = ca * 512;
  }

  // ---- fragment addressing
  const int fr = lane & 15;
  const int fq = lane >> 4;
  const int sw = fr & 7;
  const int cB0 = (fq ^ sw) * 8;          // kk=0 chunk offset (shorts)
  const int cB1 = ((4 | fq) ^ sw) * 8;    // kk=1 chunk offset
  const int rowOffB = (wn * 64 + fr) * 64;
  // A direct: lane reads A[mBase + wm*64 + mi*16 + fr][k0 + kk*32 + fq*8 ..+8]
  const __hip_bfloat16* aPtr = A + (size_t)(mBase + wm * 64 + fr) * K_DIM + fq * 8;

  bf16x8_t aR0[8], aR1[8];  // [mi*2+kk], register double-buffer

#define STAGE_B(buf, k0)                                      \
  {                                                           \
    _Pragma("unroll")                                         \
    for (int j = 0; j < 4; j++)                               \
      gload_lds16(bSrc[j] + (k0), &Bs[buf][sDst[j]]);         \
  }

#define LOAD_A(dst, k0)                                                         \
  {                                                                             \
    _Pragma("unroll")                                                           \
    for (int mi = 0; mi < 4; mi++)                                              \
      _Pragma("unroll")                                                         \
      for (int kk = 0; kk < 2; kk++)                                            \
        dst[mi * 2 + kk] =                                                      \
            *(const bf16x8_t*)(aPtr + (size_t)mi * 16 * K_DIM + (k0) + kk * 32);\
  }

#define COMPUTE(buf, aR)                                                        \
  {                                                                             \
    bf16x8_t bfr[4];                                                            \
    _Pragma("unroll")                                                           \
    for (int ni = 0; ni < 4; ni++) bfr[ni] = *(const bf16x8_t*)(&Bs[buf][rowOffB + ni * 1024 + cB0]); \
    _Pragma("unroll")                                                           \
    for (int mi = 0; mi < 4; mi++)                                              \
      _Pragma("unroll")                                                         \
      for (int ni = 0; ni < 4; ni++)                                            \
        acc[mi][ni] = __builtin_amdgcn_mfma_f32_16x16x32_bf16(aR[mi * 2], bfr[ni], acc[mi][ni], 0, 0, 0); \
    _Pragma("unroll")                                                           \
    for (int ni = 0; ni < 4; ni++) bfr[ni] = *(const bf16x8_t*)(&Bs[buf][rowOffB + ni * 1024 + cB1]); \
    _Pragma("unroll")                                                           \
    for (int mi = 0; mi < 4; mi++)                                              \
      _Pragma("unroll")                                                         \
      for (int ni = 0; ni < 4; ni++)                                            \
        acc[mi][ni] = __builtin_amdgcn_mfma_f32_16x16x32_bf16(aR[mi * 2 + 1], bfr[ni], acc[mi][ni], 0, 0, 0); \
  }

  LOAD_A(aR0, 0)
  STAGE_B(0, 0)
  for (int k0 = 0; k0 < K_DIM - 128; k0 += 128) {
    __syncthreads();                 // publish B buf0 (k0)
    STAGE_B(1, k0 + 64)              // async, covered by COMPUTE(0)
    LOAD_A(aR1, k0 + 64)             // global->VGPR, covered by COMPUTE(0)
    COMPUTE(0, aR0)
    __syncthreads();                 // publish B buf1 (k0+64)
    STAGE_B(0, k0 + 128)
    LOAD_A(aR0, k0 + 128)
    COMPUTE(1, aR1)
  }
  __syncthreads();
  STAGE_B(1, K_DIM - 64)
  LOAD_A(aR1, K_DIM - 64)
  COMPUTE(0, aR0)
  __syncthreads();
  COMPUTE(1, aR1)
#undef STAGE_B
#undef LOAD_A
#undef COMPUTE

  // epilogue: D row = fq*4 + reg, col = fr (m89-verified C/D layout)
  const int mRow = mBase + wm * 64;
  const int nCol = nBase + wn * 64;
#pragma unroll
  for (int mi = 0; mi < 4; mi++) {
#pragma unroll
    for (int ni = 0; ni < 4; ni++) {
      const int n  = nCol + ni * 16 + fr;
      const int m0 = mRow + mi * 16 + fq * 4;
#pragma unroll
      for (int r = 0; r < 4; r++) {
        float v = acc[mi][ni][r];
        size_t j = (size_t)(m0 + r) * N_DIM + n;
        if (EPI == 0) {
          Hout[j] = __float2bfloat16(fmaxf(v, 0.0f));
        } else {
          unsigned bits = threefry_mask_bits((unsigned)j);
          float y  = (bits < 0xC0000000u) ? v * (1.0f / 0.75f) : 0.0f;
          Fout[j]  = __bfloat162float(Xn[j]) + y;
        }
      }
    }
  }
}

extern "C" void kernel_launch(void* const* d_in, const int* in_sizes, int n_in,
                              void* d_out, int out_size, void* d_ws, size_t ws_size,
                              hipStream_t stream) {
  (void)in_sizes; (void)n_in; (void)out_size; (void)ws_size;
  const float* X  = (const float*)d_in[0];
  const float* W1 = (const float*)d_in[1];
  const float* W2 = (const float*)d_in[2];
  float* out = (float*)d_out;

  unsigned char* ws = (unsigned char*)d_ws;
  __hip_bfloat16* Xn  = (__hip_bfloat16*)(ws);                       // 32 MB
  __hip_bfloat16* H   = (__hip_bfloat16*)(ws + ((size_t)32 << 20));  // 32 MB
  __hip_bfloat16* W1t = (__hip_bfloat16*)(ws + ((size_t)64 << 20));  //  8 MB
  __hip_bfloat16* W2t = (__hip_bfloat16*)(ws + ((size_t)72 << 20));  //  8 MB

  wt_kernel<<<dim3(64, 64, 2), dim3(32, 8, 1), 0, stream>>>(W1, W2, W1t, W2t);
  ln_kernel<<<M_DIM, 256, 0, stream>>>(X, Xn);
  gemm128<0><<<dim3(M_DIM / 128, N_DIM / 128), 256, 0, stream>>>(Xn, W1t, nullptr, H, nullptr);
  gemm128<1><<<dim3(M_DIM / 128, N_DIM / 128), 256, 0, stream>>>(H, W2t, Xn, nullptr, out);
}